// Round 9
// baseline (620.054 us; speedup 1.0000x reference)
//
#include <hip/hip_runtime.h>

#define NVN 20000
#define NCN 20000
#define NE  500000
#define HID 64
#define NLAYER 3
#define TN 40      // nodes per MLP tile
#define BSH 8      // bin shift: 256 nodes/bin
#define NB 79      // ceil(20000/256) bins
#define P1E 2048   // edges per scatter_p1 block -> 245 blocks (coverage + 245-deep chains)

__device__ __forceinline__ float relu_(float x) { return fmaxf(x, 0.0f); }

// ---------------- CSR build ----------------
__global__ __launch_bounds__(256) void hist2_kernel(
    const int* __restrict__ dstA, const int* __restrict__ dstB,
    int* __restrict__ degA, int* __restrict__ degB)
{
    int e = blockIdx.x * 256 + threadIdx.x;
    if (e < NE) {
        atomicAdd(&degA[dstA[e]], 1);
        atomicAdd(&degB[dstB[e]], 1);
    }
}

// 2 blocks of 1024 threads; block 0 -> A, block 1 -> B (NVN == NCN)
// Also emits the NB bin-cursor bases (rowptr[b*256]) for the binned scatter.
__global__ __launch_bounds__(1024) void scan2_kernel(
    const int* __restrict__ degA, int* __restrict__ rowptrA, int* __restrict__ bincurA,
    const int* __restrict__ degB, int* __restrict__ rowptrB, int* __restrict__ bincurB)
{
    const int n = NCN;
    const int* deg = blockIdx.x ? degB : degA;
    int* rowptr    = blockIdx.x ? rowptrB : rowptrA;
    int* bincur    = blockIdx.x ? bincurB : bincurA;
    __shared__ int part[1024];
    int t = threadIdx.x;
    int chunk = (n + 1023) / 1024;
    int base = t * chunk;
    int sum = 0;
    for (int i = 0; i < chunk; ++i) {
        int idx = base + i;
        if (idx < n) sum += deg[idx];
    }
    part[t] = sum;
    __syncthreads();
    for (int off = 1; off < 1024; off <<= 1) {
        int v = (t >= off) ? part[t - off] : 0;
        __syncthreads();
        part[t] += v;
        __syncthreads();
    }
    int run = (t == 0) ? 0 : part[t - 1];
    for (int i = 0; i < chunk; ++i) {
        int idx = base + i;
        if (idx < n) {
            int d = deg[idx];
            rowptr[idx] = run;
            run += d;
        }
    }
    if (t == 1023) rowptr[n] = part[1023];
    __syncthreads();
    if (t < NB) bincur[t] = rowptr[t << BSH];
}

// ---------------- Binned scatter pass 1: edges -> bin-staged ----------------
// 2048 edges/block, 245 blocks: full CU coverage (R8's 62-block version was
// latency-exposed at 2.3% occupancy) AND moderate 245-deep global-atomic
// chains (R7's 1954-deep queuing was the 58 us stall).
__global__ __launch_bounds__(256) void scatter_p1_kernel(
    const int* __restrict__ eiA, const float* __restrict__ ewA,
    int* __restrict__ bincurA, int2* __restrict__ stageA,
    const int* __restrict__ eiB, const float* __restrict__ ewB,
    int* __restrict__ bincurB, int2* __restrict__ stageB)
{
    __shared__ int rnk[P1E];            // 8 KB
    __shared__ int cnt[NB], base_[NB];
    int t = threadIdx.x;
    int e0 = blockIdx.x * P1E;

    for (int g = 0; g < 2; ++g) {
        const int* ei   = g ? eiB : eiA;
        const float* ew = g ? ewB : ewA;
        int* bincur     = g ? bincurB : bincurA;
        int2* stage     = g ? stageB : stageA;

        if (t < NB) cnt[t] = 0;
        __syncthreads();
        for (int i = t; i < P1E; i += 256) {
            int e = e0 + i;
            if (e < NE) {
                int d = ei[NE + e];
                rnk[i] = atomicAdd(&cnt[d >> BSH], 1);
            }
        }
        __syncthreads();
        if (t < NB && cnt[t] > 0) base_[t] = atomicAdd(&bincur[t], cnt[t]);
        __syncthreads();
        for (int i = t; i < P1E; i += 256) {
            int e = e0 + i;
            if (e < NE) {
                int s = ei[e], d = ei[NE + e];
                float w = ew[e];
                stage[base_[d >> BSH] + rnk[i]] =
                    make_int2((int)((unsigned)s | ((unsigned)d << 16)), __float_as_int(w));
            }
        }
        __syncthreads();
    }
}

// ---------------- Binned scatter pass 2: staged -> final CSR slots ----------
// one block per (graph, bin) = 158 blocks; final writes land in the bin's
// ~50KB L2-resident region -> each line written back once.
__global__ __launch_bounds__(1024) void scatter_p2_kernel(
    const int* __restrict__ rowptrA, const int2* __restrict__ stageA,
    int2* __restrict__ pairA,
    const int* __restrict__ rowptrB, const int2* __restrict__ stageB,
    int2* __restrict__ pairB)
{
    __shared__ int cur[1 << BSH];
    int g = blockIdx.x / NB;
    int b = blockIdx.x % NB;
    const int* rowptr = g ? rowptrB : rowptrA;
    const int2* stage = g ? stageB : stageA;
    int2* pair        = g ? pairB : pairA;

    int d0 = b << BSH;
    int d1 = min(d0 + (1 << BSH), NCN);
    int nd = d1 - d0;
    int t = threadIdx.x;
    if (t < nd) cur[t] = rowptr[d0 + t];
    __syncthreads();

    int estart = rowptr[d0], eend = rowptr[d1];
    for (int e = estart + t; e < eend; e += 1024) {
        int2 s = stage[e];
        unsigned u = (unsigned)s.x;
        int src = (int)(u & 0xFFFFu);
        int dst = (int)(u >> 16);
        int p = atomicAdd(&cur[dst - d0], 1);
        pair[p] = make_int2(src, s.y);
    }
}

// ---------------- Encoders (both node sets in one dispatch) ----------------
__global__ __launch_bounds__(256) void encode2_kernel(
    const float* __restrict__ xv, const float* __restrict__ pev,
    const float* __restrict__ ewv, const float* __restrict__ ebv,
    const float* __restrict__ pw1v, const float* __restrict__ pb1v,
    const float* __restrict__ pw2v, const float* __restrict__ pb2v,
    const float* __restrict__ xc, const float* __restrict__ pec,
    const float* __restrict__ ewc, const float* __restrict__ ebc,
    const float* __restrict__ pw1c, const float* __restrict__ pb1c,
    const float* __restrict__ pw2c, const float* __restrict__ pb2c,
    float* __restrict__ outv, float* __restrict__ outc)
{
    __shared__ float sh[4][64];
    const int VB = (NVN + 3) / 4;
    int wave = threadIdx.x >> 6, lane = threadIdx.x & 63;
    int b = blockIdx.x;
    bool isC = (b >= VB);
    const float* x   = isC ? xc : xv;
    const float* pe  = isC ? pec : pev;
    const float* ew  = isC ? ewc : ewv;
    const float* eb  = isC ? ebc : ebv;
    const float* pw1 = isC ? pw1c : pw1v;
    const float* pb1 = isC ? pb1c : pb1v;
    const float* pw2 = isC ? pw2c : pw2v;
    const float* pb2 = isC ? pb2c : pb2v;
    float* out = isC ? outc : outv;
    int N = isC ? NCN : NVN;
    int n = (isC ? b - VB : b) * 4 + wave;
    if (n >= N) return;

    float accp = pb1[lane], accm = accp;
#pragma unroll
    for (int k = 0; k < 8; ++k) {
        float p = pe[n * 8 + k];
        float w = pw1[k * 64 + lane];
        accp += p * w;
        accm -= p * w;
    }
    float hs = 0.5f * (relu_(accp) + relu_(accm));
    float* my = sh[wave];
    my[lane] = hs;
    __builtin_amdgcn_wave_barrier();

    int col = lane & 31;
    float peo = pb2[col];
#pragma unroll
    for (int k = 0; k < 64; k += 4) {
        float4 hv = *(const float4*)(my + k);
        peo = fmaf(hv.x, pw2[(k + 0) * 32 + col], peo);
        peo = fmaf(hv.y, pw2[(k + 1) * 32 + col], peo);
        peo = fmaf(hv.z, pw2[(k + 2) * 32 + col], peo);
        peo = fmaf(hv.w, pw2[(k + 3) * 32 + col], peo);
    }
    float lino = x[n * 2 + 0] * ew[col] + x[n * 2 + 1] * ew[32 + col] + eb[col];
    float h = (lane < 32) ? lino : peo;
    out[n * 64 + lane] = relu_(h);
}

// ---------------- Edge aggregation: online softmax, wave per dst node ------
// Single masked 16-wide loop, two accumulator states merged at the end.
// Padded slots (msg=-1e30) contribute exp(-inf)=0 to a non-empty state; an
// all-padded chunk only touches a still-empty state (m stays -1e30) which the
// final merge scales by exp(-1e30-M)=0.
__global__ __launch_bounds__(256) void edge_agg_kernel(
    const float* __restrict__ xsrc,   // [Nsrc,64]
    const float* __restrict__ xdst,   // [Ndst,64]
    const int* __restrict__ rowptr,   // [Ndst+1]
    const int2* __restrict__ pair,    // [E] (src, bitcast(w)), dst-sorted
    const float* __restrict__ lew,    // [64]
    const float* __restrict__ leb,    // [64]
    float* __restrict__ oa,           // [Ndst,64]  agg + xdst
    int N)
{
    int wave = threadIdx.x >> 6, lane = threadIdx.x & 63;
    int n = blockIdx.x * 4 + wave;
    if (n >= N) return;

    int start = rowptr[n], end = rowptr[n + 1];
    float lw = lew[lane], lb = leb[lane];

    float m0 = -1e30f, den0 = 0.0f, num0 = 0.0f;
    float m1 = -1e30f, den1 = 0.0f, num1 = 0.0f;
    int last = end - 1;   // only used when loop body executes (end > start)
    for (int j = start; j < end; j += 16) {
        int idx[16]; float wv[16], msg[16]; bool val[16];
#pragma unroll
        for (int c = 0; c < 16; ++c) {
            int jj = j + c;
            val[c] = jj < end;
            int jc = val[c] ? jj : last;
            int2 p = pair[jc];
            idx[c] = p.x;
            wv[c] = __int_as_float(p.y);
        }
#pragma unroll
        for (int c = 0; c < 16; ++c) {
            float xv = xsrc[idx[c] * 64 + lane];
            float tm = relu_(fmaf(wv[c], lw, xv + lb)) + 1e-7f;
            msg[c] = val[c] ? tm : -1e30f;
        }
        // state 0 <- msg[0..7]
        {
            float a0 = fmaxf(msg[0], msg[1]), a1 = fmaxf(msg[2], msg[3]);
            float a2 = fmaxf(msg[4], msg[5]), a3 = fmaxf(msg[6], msg[7]);
            float mnew = fmaxf(m0, fmaxf(fmaxf(a0, a1), fmaxf(a2, a3)));
            float sc = __expf(m0 - mnew);
            float cd = 0.0f, cn = 0.0f;
#pragma unroll
            for (int c = 0; c < 8; ++c) {
                float e = __expf(msg[c] - mnew);
                cd += e;
                cn = fmaf(e, msg[c], cn);
            }
            den0 = fmaf(den0, sc, cd);
            num0 = fmaf(num0, sc, cn);
            m0 = mnew;
        }
        // state 1 <- msg[8..15]
        {
            float a0 = fmaxf(msg[8], msg[9]), a1 = fmaxf(msg[10], msg[11]);
            float a2 = fmaxf(msg[12], msg[13]), a3 = fmaxf(msg[14], msg[15]);
            float mnew = fmaxf(m1, fmaxf(fmaxf(a0, a1), fmaxf(a2, a3)));
            float sc = __expf(m1 - mnew);
            float cd = 0.0f, cn = 0.0f;
#pragma unroll
            for (int c = 8; c < 16; ++c) {
                float e = __expf(msg[c] - mnew);
                cd += e;
                cn = fmaf(e, msg[c], cn);
            }
            den1 = fmaf(den1, sc, cd);
            num1 = fmaf(num1, sc, cn);
            m1 = mnew;
        }
    }
    // merge (empty state: m=-1e30 -> scale 0; both empty: den=0 -> agg 0)
    float M = fmaxf(m0, m1);
    float s0 = __expf(m0 - M), s1 = __expf(m1 - M);
    float den = den0 * s0 + den1 * s1;
    float num = num0 * s0 + num1 * s1;

    oa[n * 64 + lane] = num / (den + 1e-16f) + xdst[n * 64 + lane];
}

// ---------------- Persistent-weights MLP + pred head ----------------------
__global__ __launch_bounds__(256) void mlp_kernel(
    const float* __restrict__ oa,    // [N,64]
    float* __restrict__ feat,        // [N,64]
    const float* __restrict__ w1,    // [64,128]
    const float* __restrict__ b1,    // [128]
    const float* __restrict__ w2,    // [128,64]
    const float* __restrict__ b2,    // [64]
    const float* __restrict__ pw1,   // [64,64]
    const float* __restrict__ pb1,   // [64]
    const float* __restrict__ pw2,   // [64]
    const float* __restrict__ pb2,   // [1]
    float* __restrict__ outp,
    int N, int layer)
{
    __shared__ float w1s[64 * 128];
    __shared__ float w2s[128 * 64];
    __shared__ float pw1s[64 * 64];
    __shared__ float b1s[128];
    __shared__ float b2s[64];
    __shared__ float pb1s[64];
    __shared__ float pw2s[64];
    __shared__ float act[TN][68];
    __shared__ float hid[TN][132];

    int tid = threadIdx.x;
    for (int i = tid; i < 64 * 128; i += 256) w1s[i] = w1[i];
    for (int i = tid; i < 128 * 64; i += 256) w2s[i] = w2[i];
    for (int i = tid; i < 64 * 64; i += 256) pw1s[i] = pw1[i];
    if (tid < 128) b1s[tid] = b1[tid];
    if (tid < 64) { b2s[tid] = b2[tid]; pb1s[tid] = pb1[tid]; pw2s[tid] = pw2[tid]; }
    float pb2v = pb2[0];

    int o4 = (tid & 31) * 4;
    int o2 = (tid & 31) * 2;
    int n5 = (tid >> 5) * 5;
    __syncthreads();

    int ntiles = N / TN;
    for (int tile = blockIdx.x; tile < ntiles; tile += gridDim.x) {
        int base = tile * TN;
        {
            const float* g = oa + (size_t)base * 64;
            for (int i = tid; i < TN * 64; i += 256)
                act[i >> 6][i & 63] = g[i];
        }
        __syncthreads();

        {
            float acc[5][4];
#pragma unroll
            for (int i = 0; i < 5; ++i)
#pragma unroll
                for (int q = 0; q < 4; ++q) acc[i][q] = b1s[o4 + q];
            for (int k = 0; k < 64; k += 4) {
                float4 a[5];
#pragma unroll
                for (int i = 0; i < 5; ++i) a[i] = *(const float4*)&act[n5 + i][k];
                float4 w0 = *(const float4*)&w1s[(k + 0) * 128 + o4];
                float4 wq1 = *(const float4*)&w1s[(k + 1) * 128 + o4];
                float4 wq2 = *(const float4*)&w1s[(k + 2) * 128 + o4];
                float4 wq3 = *(const float4*)&w1s[(k + 3) * 128 + o4];
#pragma unroll
                for (int i = 0; i < 5; ++i) {
                    acc[i][0] = fmaf(a[i].x, w0.x, acc[i][0]);
                    acc[i][1] = fmaf(a[i].x, w0.y, acc[i][1]);
                    acc[i][2] = fmaf(a[i].x, w0.z, acc[i][2]);
                    acc[i][3] = fmaf(a[i].x, w0.w, acc[i][3]);
                    acc[i][0] = fmaf(a[i].y, wq1.x, acc[i][0]);
                    acc[i][1] = fmaf(a[i].y, wq1.y, acc[i][1]);
                    acc[i][2] = fmaf(a[i].y, wq1.z, acc[i][2]);
                    acc[i][3] = fmaf(a[i].y, wq1.w, acc[i][3]);
                    acc[i][0] = fmaf(a[i].z, wq2.x, acc[i][0]);
                    acc[i][1] = fmaf(a[i].z, wq2.y, acc[i][1]);
                    acc[i][2] = fmaf(a[i].z, wq2.z, acc[i][2]);
                    acc[i][3] = fmaf(a[i].z, wq2.w, acc[i][3]);
                    acc[i][0] = fmaf(a[i].w, wq3.x, acc[i][0]);
                    acc[i][1] = fmaf(a[i].w, wq3.y, acc[i][1]);
                    acc[i][2] = fmaf(a[i].w, wq3.z, acc[i][2]);
                    acc[i][3] = fmaf(a[i].w, wq3.w, acc[i][3]);
                }
            }
#pragma unroll
            for (int i = 0; i < 5; ++i) {
                float4 h4 = make_float4(relu_(acc[i][0]), relu_(acc[i][1]),
                                        relu_(acc[i][2]), relu_(acc[i][3]));
                *(float4*)&hid[n5 + i][o4] = h4;
            }
        }
        __syncthreads();

        {
            float acc[5][2];
#pragma unroll
            for (int i = 0; i < 5; ++i) { acc[i][0] = b2s[o2]; acc[i][1] = b2s[o2 + 1]; }
            for (int k = 0; k < 128; k += 4) {
                float4 a[5];
#pragma unroll
                for (int i = 0; i < 5; ++i) a[i] = *(const float4*)&hid[n5 + i][k];
                float2 w0 = *(const float2*)&w2s[(k + 0) * 64 + o2];
                float2 wq1 = *(const float2*)&w2s[(k + 1) * 64 + o2];
                float2 wq2 = *(const float2*)&w2s[(k + 2) * 64 + o2];
                float2 wq3 = *(const float2*)&w2s[(k + 3) * 64 + o2];
#pragma unroll
                for (int i = 0; i < 5; ++i) {
                    acc[i][0] = fmaf(a[i].x, w0.x, acc[i][0]);
                    acc[i][1] = fmaf(a[i].x, w0.y, acc[i][1]);
                    acc[i][0] = fmaf(a[i].y, wq1.x, acc[i][0]);
                    acc[i][1] = fmaf(a[i].y, wq1.y, acc[i][1]);
                    acc[i][0] = fmaf(a[i].z, wq2.x, acc[i][0]);
                    acc[i][1] = fmaf(a[i].z, wq2.y, acc[i][1]);
                    acc[i][0] = fmaf(a[i].w, wq3.x, acc[i][0]);
                    acc[i][1] = fmaf(a[i].w, wq3.y, acc[i][1]);
                }
            }
#pragma unroll
            for (int i = 0; i < 5; ++i) {
                float2 r2 = make_float2(acc[i][0], acc[i][1]);
                *(float2*)&feat[(size_t)(base + n5 + i) * 64 + o2] = r2;
                *(float2*)&act[n5 + i][o2] = r2;
            }
        }
        __syncthreads();

        {
            float acc[5][2];
#pragma unroll
            for (int i = 0; i < 5; ++i) { acc[i][0] = pb1s[o2]; acc[i][1] = pb1s[o2 + 1]; }
            for (int k = 0; k < 64; k += 4) {
                float4 a[5];
#pragma unroll
                for (int i = 0; i < 5; ++i) a[i] = *(const float4*)&act[n5 + i][k];
                float2 w0 = *(const float2*)&pw1s[(k + 0) * 64 + o2];
                float2 wq1 = *(const float2*)&pw1s[(k + 1) * 64 + o2];
                float2 wq2 = *(const float2*)&pw1s[(k + 2) * 64 + o2];
                float2 wq3 = *(const float2*)&pw1s[(k + 3) * 64 + o2];
#pragma unroll
                for (int i = 0; i < 5; ++i) {
                    acc[i][0] = fmaf(a[i].x, w0.x, acc[i][0]);
                    acc[i][1] = fmaf(a[i].x, w0.y, acc[i][1]);
                    acc[i][0] = fmaf(a[i].y, wq1.x, acc[i][0]);
                    acc[i][1] = fmaf(a[i].y, wq1.y, acc[i][1]);
                    acc[i][0] = fmaf(a[i].z, wq2.x, acc[i][0]);
                    acc[i][1] = fmaf(a[i].z, wq2.y, acc[i][1]);
                    acc[i][0] = fmaf(a[i].w, wq3.x, acc[i][0]);
                    acc[i][1] = fmaf(a[i].w, wq3.y, acc[i][1]);
                }
            }
            float pw2a = pw2s[o2], pw2b = pw2s[o2 + 1];
            float ps[5];
#pragma unroll
            for (int i = 0; i < 5; ++i)
                ps[i] = relu_(acc[i][0]) * pw2a + relu_(acc[i][1]) * pw2b;
#pragma unroll
            for (int msk = 16; msk >= 1; msk >>= 1) {
#pragma unroll
                for (int i = 0; i < 5; ++i)
                    ps[i] += __shfl_xor(ps[i], msk, 64);
            }
            if ((tid & 31) == 0) {
#pragma unroll
                for (int i = 0; i < 5; ++i)
                    outp[(size_t)(base + n5 + i) * NLAYER + layer] = ps[i] + pb2v;
            }
        }
        __syncthreads();
    }
}

extern "C" void kernel_launch(void* const* d_in, const int* in_sizes, int n_in,
                              void* d_out, int out_size, void* d_ws, size_t ws_size,
                              hipStream_t stream)
{
    const float* x_vals   = (const float*)d_in[0];
    const float* x_cons   = (const float*)d_in[1];
    const float* pe_vals  = (const float*)d_in[2];
    const float* pe_cons  = (const float*)d_in[3];
    const int*   ei_v2c   = (const int*)d_in[4];   // [2,E]
    const int*   ei_c2v   = (const int*)d_in[5];   // [2,E]
    const float* ew_v2c   = (const float*)d_in[6]; // [E,1]
    const float* ew_c2v   = (const float*)d_in[7];
    const float* enc_vals_w = (const float*)d_in[8];
    const float* enc_vals_b = (const float*)d_in[9];
    const float* pe_vals_w1 = (const float*)d_in[10];
    const float* pe_vals_b1 = (const float*)d_in[11];
    const float* pe_vals_w2 = (const float*)d_in[12];
    const float* pe_vals_b2 = (const float*)d_in[13];
    const float* enc_cons_w = (const float*)d_in[14];
    const float* enc_cons_b = (const float*)d_in[15];
    const float* pe_cons_w1 = (const float*)d_in[16];
    const float* pe_cons_b1 = (const float*)d_in[17];
    const float* pe_cons_w2 = (const float*)d_in[18];
    const float* pe_cons_b2 = (const float*)d_in[19];
    const float* v2c_edge_w = (const float*)d_in[20]; // [NL,1,64]
    const float* v2c_edge_b = (const float*)d_in[21]; // [NL,64]
    const float* v2c_w1     = (const float*)d_in[22]; // [NL,64,128]
    const float* v2c_b1     = (const float*)d_in[23]; // [NL,128]
    const float* v2c_w2     = (const float*)d_in[24]; // [NL,128,64]
    const float* v2c_b2     = (const float*)d_in[25]; // [NL,64]
    const float* c2v_edge_w = (const float*)d_in[26];
    const float* c2v_edge_b = (const float*)d_in[27];
    const float* c2v_w1     = (const float*)d_in[28];
    const float* c2v_b1     = (const float*)d_in[29];
    const float* c2v_w2     = (const float*)d_in[30];
    const float* c2v_b2     = (const float*)d_in[31];
    const float* pred_vals_w1 = (const float*)d_in[32];
    const float* pred_vals_b1 = (const float*)d_in[33];
    const float* pred_vals_w2 = (const float*)d_in[34];
    const float* pred_vals_b2 = (const float*)d_in[35];
    const float* pred_cons_w1 = (const float*)d_in[36];
    const float* pred_cons_b1 = (const float*)d_in[37];
    const float* pred_cons_w2 = (const float*)d_in[38];
    const float* pred_cons_b2 = (const float*)d_in[39];

    float* out = (float*)d_out;
    float* out_c = out + (size_t)NVN * NLAYER;

    const size_t NF = (size_t)NVN * 64;

    // Workspace layout
    float* ws     = (float*)d_ws;
    float* feat_v = ws;                 // NF
    float* feat_c = feat_v + NF;        // NF
    float* oa     = feat_c + NF;        // NF
    int2* v2c_pair  = (int2*)(oa + NF);        // NE
    int2* c2v_pair  = v2c_pair + NE;           // NE
    int2* v2c_stage = c2v_pair + NE;           // NE
    int2* c2v_stage = v2c_stage + NE;          // NE
    int* ip = (int*)(c2v_stage + NE);
    int* v2c_deg    = ip; ip += NCN;    // adjacent degs -> one memset
    int* c2v_deg    = ip; ip += NVN;
    int* v2c_rowptr = ip; ip += NCN + 1;
    int* c2v_rowptr = ip; ip += NVN + 1;
    int* v2c_bincur = ip; ip += NB;
    int* c2v_bincur = ip; ip += NB;

    const int eb256 = (NE + 255) / 256;
    const int p1b   = (NE + P1E - 1) / P1E;   // 245

    // CSR build (edge structure is layer-invariant)
    hipMemsetAsync(v2c_deg, 0, (size_t)(NCN + NVN) * sizeof(int), stream);
    hist2_kernel<<<eb256, 256, 0, stream>>>(ei_v2c + NE, ei_c2v + NE, v2c_deg, c2v_deg);
    scan2_kernel<<<2, 1024, 0, stream>>>(v2c_deg, v2c_rowptr, v2c_bincur,
                                         c2v_deg, c2v_rowptr, c2v_bincur);
    scatter_p1_kernel<<<p1b, 256, 0, stream>>>(
        ei_v2c, ew_v2c, v2c_bincur, v2c_stage,
        ei_c2v, ew_c2v, c2v_bincur, c2v_stage);
    scatter_p2_kernel<<<2 * NB, 1024, 0, stream>>>(
        v2c_rowptr, v2c_stage, v2c_pair,
        c2v_rowptr, c2v_stage, c2v_pair);

    // Encoders
    encode2_kernel<<<(NVN + 3) / 4 + (NCN + 3) / 4, 256, 0, stream>>>(
        x_vals, pe_vals, enc_vals_w, enc_vals_b,
        pe_vals_w1, pe_vals_b1, pe_vals_w2, pe_vals_b2,
        x_cons, pe_cons, enc_cons_w, enc_cons_b,
        pe_cons_w1, pe_cons_b1, pe_cons_w2, pe_cons_b2,
        feat_v, feat_c);

    for (int i = 0; i < NLAYER; ++i) {
        // v2c: src = vals, dst = cons
        edge_agg_kernel<<<(NCN + 3) / 4, 256, 0, stream>>>(
            feat_v, feat_c, v2c_rowptr, v2c_pair,
            v2c_edge_w + (size_t)i * HID, v2c_edge_b + (size_t)i * HID,
            oa, NCN);
        mlp_kernel<<<250, 256, 0, stream>>>(
            oa, feat_c,
            v2c_w1 + (size_t)i * 8192, v2c_b1 + (size_t)i * 128,
            v2c_w2 + (size_t)i * 8192, v2c_b2 + (size_t)i * 64,
            pred_cons_w1, pred_cons_b1, pred_cons_w2, pred_cons_b2,
            out_c, NCN, i);
        // c2v: src = cons (updated), dst = vals
        edge_agg_kernel<<<(NVN + 3) / 4, 256, 0, stream>>>(
            feat_c, feat_v, c2v_rowptr, c2v_pair,
            c2v_edge_w + (size_t)i * HID, c2v_edge_b + (size_t)i * HID,
            oa, NVN);
        mlp_kernel<<<250, 256, 0, stream>>>(
            oa, feat_v,
            c2v_w1 + (size_t)i * 8192, c2v_b1 + (size_t)i * 128,
            c2v_w2 + (size_t)i * 8192, c2v_b2 + (size_t)i * 64,
            pred_vals_w1, pred_vals_b1, pred_vals_w2, pred_vals_b2,
            out, NVN, i);
    }
}

// Round 10
// 514.888 us; speedup vs baseline: 1.2043x; 1.2043x over previous
//
#include <hip/hip_runtime.h>

#define NVN 20000
#define NCN 20000
#define NE  500000
#define HID 64
#define NLAYER 3
#define TN 40      // nodes per MLP tile
#define BSH 8      // bin shift: 256 nodes/bin
#define NB 79      // ceil(20000/256) bins
#define P1E 2048   // edges per histogram/scatter block -> 245 blocks

__device__ __forceinline__ float relu_(float x) { return fmaxf(x, 0.0f); }

// ---------------- Bin histogram: LDS counts + 1 global atomic per bin/block
__global__ __launch_bounds__(256) void binhist_kernel(
    const int* __restrict__ dstA, const int* __restrict__ dstB,
    int* __restrict__ binszA, int* __restrict__ binszB)   // zeroed
{
    __shared__ int cA[NB], cB[NB];
    int t = threadIdx.x;
    int e0 = blockIdx.x * P1E;
    if (t < NB) { cA[t] = 0; cB[t] = 0; }
    __syncthreads();
    for (int i = t; i < P1E; i += 256) {
        int e = e0 + i;
        if (e < NE) {
            atomicAdd(&cA[dstA[e] >> BSH], 1);
            atomicAdd(&cB[dstB[e] >> BSH], 1);
        }
    }
    __syncthreads();
    if (t < NB) {
        if (cA[t] > 0) atomicAdd(&binszA[t], cA[t]);
        if (cB[t] > 0) atomicAdd(&binszB[t], cB[t]);
    }
}

// ---------------- Tiny 79-bin scan; block 0 -> A, block 1 -> B ----------------
__global__ __launch_bounds__(256) void binscan_kernel(
    const int* __restrict__ binszA, int* __restrict__ binbaseA, int* __restrict__ bincurA,
    const int* __restrict__ binszB, int* __restrict__ binbaseB, int* __restrict__ bincurB)
{
    const int* binsz = blockIdx.x ? binszB : binszA;
    int* binbase     = blockIdx.x ? binbaseB : binbaseA;
    int* bincur      = blockIdx.x ? bincurB : bincurA;
    __shared__ int p[256];
    int t = threadIdx.x;
    p[t] = (t < NB) ? binsz[t] : 0;
    __syncthreads();
    for (int off = 1; off < 256; off <<= 1) {
        int v = (t >= off) ? p[t - off] : 0;
        __syncthreads();
        p[t] += v;
        __syncthreads();
    }
    if (t < NB) { int b = (t == 0) ? 0 : p[t - 1]; binbase[t] = b; bincur[t] = b; }
    if (t == NB) binbase[NB] = p[NB - 1];   // == NE
}

// ---------------- Binned scatter pass 1: edges -> bin-staged ----------------
// stage element: (src | dst<<16, bitcast(w)); both < 2^16.
__global__ __launch_bounds__(256) void scatter_p1_kernel(
    const int* __restrict__ eiA, const float* __restrict__ ewA,
    int* __restrict__ bincurA, int2* __restrict__ stageA,
    const int* __restrict__ eiB, const float* __restrict__ ewB,
    int* __restrict__ bincurB, int2* __restrict__ stageB)
{
    __shared__ int rnk[P1E];            // 8 KB
    __shared__ int cnt[NB], base_[NB];
    int t = threadIdx.x;
    int e0 = blockIdx.x * P1E;

    for (int g = 0; g < 2; ++g) {
        const int* ei   = g ? eiB : eiA;
        const float* ew = g ? ewB : ewA;
        int* bincur     = g ? bincurB : bincurA;
        int2* stage     = g ? stageB : stageA;

        if (t < NB) cnt[t] = 0;
        __syncthreads();
        for (int i = t; i < P1E; i += 256) {
            int e = e0 + i;
            if (e < NE) {
                int d = ei[NE + e];
                rnk[i] = atomicAdd(&cnt[d >> BSH], 1);
            }
        }
        __syncthreads();
        if (t < NB && cnt[t] > 0) base_[t] = atomicAdd(&bincur[t], cnt[t]);
        __syncthreads();
        for (int i = t; i < P1E; i += 256) {
            int e = e0 + i;
            if (e < NE) {
                int s = ei[e], d = ei[NE + e];
                float w = ew[e];
                stage[base_[d >> BSH] + rnk[i]] =
                    make_int2((int)((unsigned)s | ((unsigned)d << 16)), __float_as_int(w));
            }
        }
        __syncthreads();
    }
}

// ---------------- Pass 2: LDS counting sort per bin; builds rowptr + pair ---
// one block per (graph, bin). Final writes land in the bin's ~50KB
// L2-resident region -> each line written back once.
__global__ __launch_bounds__(1024) void scatter_p2_kernel(
    const int* __restrict__ binbaseA, const int2* __restrict__ stageA,
    int* __restrict__ rowptrA, int2* __restrict__ pairA,
    const int* __restrict__ binbaseB, const int2* __restrict__ stageB,
    int* __restrict__ rowptrB, int2* __restrict__ pairB)
{
    __shared__ int deg[256], pfx[256], cur[256];
    int g = blockIdx.x / NB;
    int b = blockIdx.x % NB;
    const int* binbase = g ? binbaseB : binbaseA;
    const int2* stage  = g ? stageB : stageA;
    int* rowptr        = g ? rowptrB : rowptrA;
    int2* pair         = g ? pairB : pairA;

    int d0 = b << BSH;
    int d1 = min(d0 + 256, NCN);   // NVN == NCN
    int nd = d1 - d0;
    int t = threadIdx.x;
    int estart = binbase[b], eend = binbase[b + 1];

    if (t < 256) deg[t] = 0;
    __syncthreads();
    for (int e = estart + t; e < eend; e += 1024) {
        int dst = (int)((unsigned)stage[e].x >> 16);
        atomicAdd(&deg[dst - d0], 1);
    }
    __syncthreads();
    if (t < 256) pfx[t] = deg[t];
    __syncthreads();
    for (int off = 1; off < 256; off <<= 1) {
        int v = (t >= off && t < 256) ? pfx[t - off] : 0;
        __syncthreads();
        if (t < 256) pfx[t] += v;
        __syncthreads();
    }
    if (t < nd) {
        int ex = estart + pfx[t] - deg[t];   // exclusive
        rowptr[d0 + t] = ex;
        cur[t] = ex;
    }
    if (t == 0) rowptr[d1] = eend;   // interior bins: next bin writes same value
    __syncthreads();
    for (int e = estart + t; e < eend; e += 1024) {
        int2 s = stage[e];
        unsigned u = (unsigned)s.x;
        int src = (int)(u & 0xFFFFu);
        int dst = (int)(u >> 16);
        int p = atomicAdd(&cur[dst - d0], 1);
        pair[p] = make_int2(src, s.y);
    }
}

// ---------------- Encoders (both node sets in one dispatch) ----------------
__global__ __launch_bounds__(256) void encode2_kernel(
    const float* __restrict__ xv, const float* __restrict__ pev,
    const float* __restrict__ ewv, const float* __restrict__ ebv,
    const float* __restrict__ pw1v, const float* __restrict__ pb1v,
    const float* __restrict__ pw2v, const float* __restrict__ pb2v,
    const float* __restrict__ xc, const float* __restrict__ pec,
    const float* __restrict__ ewc, const float* __restrict__ ebc,
    const float* __restrict__ pw1c, const float* __restrict__ pb1c,
    const float* __restrict__ pw2c, const float* __restrict__ pb2c,
    float* __restrict__ outv, float* __restrict__ outc)
{
    __shared__ float sh[4][64];
    const int VB = (NVN + 3) / 4;
    int wave = threadIdx.x >> 6, lane = threadIdx.x & 63;
    int b = blockIdx.x;
    bool isC = (b >= VB);
    const float* x   = isC ? xc : xv;
    const float* pe  = isC ? pec : pev;
    const float* ew  = isC ? ewc : ewv;
    const float* eb  = isC ? ebc : ebv;
    const float* pw1 = isC ? pw1c : pw1v;
    const float* pb1 = isC ? pb1c : pb1v;
    const float* pw2 = isC ? pw2c : pw2v;
    const float* pb2 = isC ? pb2c : pb2v;
    float* out = isC ? outc : outv;
    int N = isC ? NCN : NVN;
    int n = (isC ? b - VB : b) * 4 + wave;
    if (n >= N) return;

    float accp = pb1[lane], accm = accp;
#pragma unroll
    for (int k = 0; k < 8; ++k) {
        float p = pe[n * 8 + k];
        float w = pw1[k * 64 + lane];
        accp += p * w;
        accm -= p * w;
    }
    float hs = 0.5f * (relu_(accp) + relu_(accm));
    float* my = sh[wave];
    my[lane] = hs;
    __builtin_amdgcn_wave_barrier();

    int col = lane & 31;
    float peo = pb2[col];
#pragma unroll
    for (int k = 0; k < 64; k += 4) {
        float4 hv = *(const float4*)(my + k);
        peo = fmaf(hv.x, pw2[(k + 0) * 32 + col], peo);
        peo = fmaf(hv.y, pw2[(k + 1) * 32 + col], peo);
        peo = fmaf(hv.z, pw2[(k + 2) * 32 + col], peo);
        peo = fmaf(hv.w, pw2[(k + 3) * 32 + col], peo);
    }
    float lino = x[n * 2 + 0] * ew[col] + x[n * 2 + 1] * ew[32 + col] + eb[col];
    float h = (lane < 32) ? lino : peo;
    out[n * 64 + lane] = relu_(h);
}

// ---------------- Edge aggregation (R8 structure): online softmax ----------
// 16-wide unmasked main loop with two accumulator states, 8-wide unmasked,
// scalar tail; states merged at the end. (R9's masked loop regressed: per-slot
// selects on the hot path.)
__global__ __launch_bounds__(256) void edge_agg_kernel(
    const float* __restrict__ xsrc,   // [Nsrc,64]
    const float* __restrict__ xdst,   // [Ndst,64]
    const int* __restrict__ rowptr,   // [Ndst+1]
    const int2* __restrict__ pair,    // [E] (src, bitcast(w)), dst-sorted
    const float* __restrict__ lew,    // [64]
    const float* __restrict__ leb,    // [64]
    float* __restrict__ oa,           // [Ndst,64]  agg + xdst
    int N)
{
    int wave = threadIdx.x >> 6, lane = threadIdx.x & 63;
    int n = blockIdx.x * 4 + wave;
    if (n >= N) return;

    int start = rowptr[n], end = rowptr[n + 1];
    float lw = lew[lane], lb = leb[lane];
    float xd = xdst[n * 64 + lane];   // independent: issue before the edge loop

    float m0 = -1e30f, den0 = 0.0f, num0 = 0.0f;
    float m1 = -1e30f, den1 = 0.0f, num1 = 0.0f;
    int j = start;
    for (; j + 16 <= end; j += 16) {
        int idx[16]; float wv[16], msg[16];
#pragma unroll
        for (int c = 0; c < 16; ++c) {
            int2 p = pair[j + c];
            idx[c] = p.x;
            wv[c] = __int_as_float(p.y);
        }
#pragma unroll
        for (int c = 0; c < 16; ++c) {
            float xv = xsrc[idx[c] * 64 + lane];
            msg[c] = relu_(fmaf(wv[c], lw, xv + lb)) + 1e-7f;
        }
        {
            float a0 = fmaxf(msg[0], msg[1]), a1 = fmaxf(msg[2], msg[3]);
            float a2 = fmaxf(msg[4], msg[5]), a3 = fmaxf(msg[6], msg[7]);
            float mnew = fmaxf(m0, fmaxf(fmaxf(a0, a1), fmaxf(a2, a3)));
            float sc = __expf(m0 - mnew);
            float cd = 0.0f, cn = 0.0f;
#pragma unroll
            for (int c = 0; c < 8; ++c) {
                float e = __expf(msg[c] - mnew);
                cd += e;
                cn = fmaf(e, msg[c], cn);
            }
            den0 = fmaf(den0, sc, cd);
            num0 = fmaf(num0, sc, cn);
            m0 = mnew;
        }
        {
            float a0 = fmaxf(msg[8], msg[9]), a1 = fmaxf(msg[10], msg[11]);
            float a2 = fmaxf(msg[12], msg[13]), a3 = fmaxf(msg[14], msg[15]);
            float mnew = fmaxf(m1, fmaxf(fmaxf(a0, a1), fmaxf(a2, a3)));
            float sc = __expf(m1 - mnew);
            float cd = 0.0f, cn = 0.0f;
#pragma unroll
            for (int c = 8; c < 16; ++c) {
                float e = __expf(msg[c] - mnew);
                cd += e;
                cn = fmaf(e, msg[c], cn);
            }
            den1 = fmaf(den1, sc, cd);
            num1 = fmaf(num1, sc, cn);
            m1 = mnew;
        }
    }
    for (; j + 8 <= end; j += 8) {
        int idx[8]; float wv[8], msg[8];
#pragma unroll
        for (int c = 0; c < 8; ++c) {
            int2 p = pair[j + c];
            idx[c] = p.x;
            wv[c] = __int_as_float(p.y);
        }
#pragma unroll
        for (int c = 0; c < 8; ++c) {
            float xv = xsrc[idx[c] * 64 + lane];
            msg[c] = relu_(fmaf(wv[c], lw, xv + lb)) + 1e-7f;
        }
        float a0 = fmaxf(msg[0], msg[1]), a1 = fmaxf(msg[2], msg[3]);
        float a2 = fmaxf(msg[4], msg[5]), a3 = fmaxf(msg[6], msg[7]);
        float mnew = fmaxf(m0, fmaxf(fmaxf(a0, a1), fmaxf(a2, a3)));
        float sc = __expf(m0 - mnew);
        float cd = 0.0f, cn = 0.0f;
#pragma unroll
        for (int c = 0; c < 8; ++c) {
            float e = __expf(msg[c] - mnew);
            cd += e;
            cn = fmaf(e, msg[c], cn);
        }
        den0 = fmaf(den0, sc, cd);
        num0 = fmaf(num0, sc, cn);
        m0 = mnew;
    }
    for (; j < end; ++j) {
        int2 p = pair[j];
        float xv = xsrc[p.x * 64 + lane];
        float msg = relu_(fmaf(__int_as_float(p.y), lw, xv + lb)) + 1e-7f;
        float mnew = fmaxf(m0, msg);
        float sc = __expf(m0 - mnew);
        float e = __expf(msg - mnew);
        den0 = fmaf(den0, sc, e);
        num0 = fmaf(num0, sc, e * msg);
        m0 = mnew;
    }
    float M = fmaxf(m0, m1);
    float s0 = __expf(m0 - M), s1 = __expf(m1 - M);
    float den = den0 * s0 + den1 * s1;
    float num = num0 * s0 + num1 * s1;

    oa[n * 64 + lane] = num / (den + 1e-16f) + xd;
}

// ---------------- Persistent-weights MLP + pred head ----------------------
__global__ __launch_bounds__(256) void mlp_kernel(
    const float* __restrict__ oa,    // [N,64]
    float* __restrict__ feat,        // [N,64]
    const float* __restrict__ w1,    // [64,128]
    const float* __restrict__ b1,    // [128]
    const float* __restrict__ w2,    // [128,64]
    const float* __restrict__ b2,    // [64]
    const float* __restrict__ pw1,   // [64,64]
    const float* __restrict__ pb1,   // [64]
    const float* __restrict__ pw2,   // [64]
    const float* __restrict__ pb2,   // [1]
    float* __restrict__ outp,
    int N, int layer)
{
    __shared__ float w1s[64 * 128];
    __shared__ float w2s[128 * 64];
    __shared__ float pw1s[64 * 64];
    __shared__ float b1s[128];
    __shared__ float b2s[64];
    __shared__ float pb1s[64];
    __shared__ float pw2s[64];
    __shared__ float act[TN][68];
    __shared__ float hid[TN][132];

    int tid = threadIdx.x;
    for (int i = tid; i < 64 * 128; i += 256) w1s[i] = w1[i];
    for (int i = tid; i < 128 * 64; i += 256) w2s[i] = w2[i];
    for (int i = tid; i < 64 * 64; i += 256) pw1s[i] = pw1[i];
    if (tid < 128) b1s[tid] = b1[tid];
    if (tid < 64) { b2s[tid] = b2[tid]; pb1s[tid] = pb1[tid]; pw2s[tid] = pw2[tid]; }
    float pb2v = pb2[0];

    int o4 = (tid & 31) * 4;
    int o2 = (tid & 31) * 2;
    int n5 = (tid >> 5) * 5;
    __syncthreads();

    int ntiles = N / TN;
    for (int tile = blockIdx.x; tile < ntiles; tile += gridDim.x) {
        int base = tile * TN;
        {
            const float* g = oa + (size_t)base * 64;
            for (int i = tid; i < TN * 64; i += 256)
                act[i >> 6][i & 63] = g[i];
        }
        __syncthreads();

        {
            float acc[5][4];
#pragma unroll
            for (int i = 0; i < 5; ++i)
#pragma unroll
                for (int q = 0; q < 4; ++q) acc[i][q] = b1s[o4 + q];
            for (int k = 0; k < 64; k += 4) {
                float4 a[5];
#pragma unroll
                for (int i = 0; i < 5; ++i) a[i] = *(const float4*)&act[n5 + i][k];
                float4 w0 = *(const float4*)&w1s[(k + 0) * 128 + o4];
                float4 wq1 = *(const float4*)&w1s[(k + 1) * 128 + o4];
                float4 wq2 = *(const float4*)&w1s[(k + 2) * 128 + o4];
                float4 wq3 = *(const float4*)&w1s[(k + 3) * 128 + o4];
#pragma unroll
                for (int i = 0; i < 5; ++i) {
                    acc[i][0] = fmaf(a[i].x, w0.x, acc[i][0]);
                    acc[i][1] = fmaf(a[i].x, w0.y, acc[i][1]);
                    acc[i][2] = fmaf(a[i].x, w0.z, acc[i][2]);
                    acc[i][3] = fmaf(a[i].x, w0.w, acc[i][3]);
                    acc[i][0] = fmaf(a[i].y, wq1.x, acc[i][0]);
                    acc[i][1] = fmaf(a[i].y, wq1.y, acc[i][1]);
                    acc[i][2] = fmaf(a[i].y, wq1.z, acc[i][2]);
                    acc[i][3] = fmaf(a[i].y, wq1.w, acc[i][3]);
                    acc[i][0] = fmaf(a[i].z, wq2.x, acc[i][0]);
                    acc[i][1] = fmaf(a[i].z, wq2.y, acc[i][1]);
                    acc[i][2] = fmaf(a[i].z, wq2.z, acc[i][2]);
                    acc[i][3] = fmaf(a[i].z, wq2.w, acc[i][3]);
                    acc[i][0] = fmaf(a[i].w, wq3.x, acc[i][0]);
                    acc[i][1] = fmaf(a[i].w, wq3.y, acc[i][1]);
                    acc[i][2] = fmaf(a[i].w, wq3.z, acc[i][2]);
                    acc[i][3] = fmaf(a[i].w, wq3.w, acc[i][3]);
                }
            }
#pragma unroll
            for (int i = 0; i < 5; ++i) {
                float4 h4 = make_float4(relu_(acc[i][0]), relu_(acc[i][1]),
                                        relu_(acc[i][2]), relu_(acc[i][3]));
                *(float4*)&hid[n5 + i][o4] = h4;
            }
        }
        __syncthreads();

        {
            float acc[5][2];
#pragma unroll
            for (int i = 0; i < 5; ++i) { acc[i][0] = b2s[o2]; acc[i][1] = b2s[o2 + 1]; }
            for (int k = 0; k < 128; k += 4) {
                float4 a[5];
#pragma unroll
                for (int i = 0; i < 5; ++i) a[i] = *(const float4*)&hid[n5 + i][k];
                float2 w0 = *(const float2*)&w2s[(k + 0) * 64 + o2];
                float2 wq1 = *(const float2*)&w2s[(k + 1) * 64 + o2];
                float2 wq2 = *(const float2*)&w2s[(k + 2) * 64 + o2];
                float2 wq3 = *(const float2*)&w2s[(k + 3) * 64 + o2];
#pragma unroll
                for (int i = 0; i < 5; ++i) {
                    acc[i][0] = fmaf(a[i].x, w0.x, acc[i][0]);
                    acc[i][1] = fmaf(a[i].x, w0.y, acc[i][1]);
                    acc[i][0] = fmaf(a[i].y, wq1.x, acc[i][0]);
                    acc[i][1] = fmaf(a[i].y, wq1.y, acc[i][1]);
                    acc[i][0] = fmaf(a[i].z, wq2.x, acc[i][0]);
                    acc[i][1] = fmaf(a[i].z, wq2.y, acc[i][1]);
                    acc[i][0] = fmaf(a[i].w, wq3.x, acc[i][0]);
                    acc[i][1] = fmaf(a[i].w, wq3.y, acc[i][1]);
                }
            }
#pragma unroll
            for (int i = 0; i < 5; ++i) {
                float2 r2 = make_float2(acc[i][0], acc[i][1]);
                *(float2*)&feat[(size_t)(base + n5 + i) * 64 + o2] = r2;
                *(float2*)&act[n5 + i][o2] = r2;
            }
        }
        __syncthreads();

        {
            float acc[5][2];
#pragma unroll
            for (int i = 0; i < 5; ++i) { acc[i][0] = pb1s[o2]; acc[i][1] = pb1s[o2 + 1]; }
            for (int k = 0; k < 64; k += 4) {
                float4 a[5];
#pragma unroll
                for (int i = 0; i < 5; ++i) a[i] = *(const float4*)&act[n5 + i][k];
                float2 w0 = *(const float2*)&pw1s[(k + 0) * 64 + o2];
                float2 wq1 = *(const float2*)&pw1s[(k + 1) * 64 + o2];
                float2 wq2 = *(const float2*)&pw1s[(k + 2) * 64 + o2];
                float2 wq3 = *(const float2*)&pw1s[(k + 3) * 64 + o2];
#pragma unroll
                for (int i = 0; i < 5; ++i) {
                    acc[i][0] = fmaf(a[i].x, w0.x, acc[i][0]);
                    acc[i][1] = fmaf(a[i].x, w0.y, acc[i][1]);
                    acc[i][0] = fmaf(a[i].y, wq1.x, acc[i][0]);
                    acc[i][1] = fmaf(a[i].y, wq1.y, acc[i][1]);
                    acc[i][0] = fmaf(a[i].z, wq2.x, acc[i][0]);
                    acc[i][1] = fmaf(a[i].z, wq2.y, acc[i][1]);
                    acc[i][0] = fmaf(a[i].w, wq3.x, acc[i][0]);
                    acc[i][1] = fmaf(a[i].w, wq3.y, acc[i][1]);
                }
            }
            float pw2a = pw2s[o2], pw2b = pw2s[o2 + 1];
            float ps[5];
#pragma unroll
            for (int i = 0; i < 5; ++i)
                ps[i] = relu_(acc[i][0]) * pw2a + relu_(acc[i][1]) * pw2b;
#pragma unroll
            for (int msk = 16; msk >= 1; msk >>= 1) {
#pragma unroll
                for (int i = 0; i < 5; ++i)
                    ps[i] += __shfl_xor(ps[i], msk, 64);
            }
            if ((tid & 31) == 0) {
#pragma unroll
                for (int i = 0; i < 5; ++i)
                    outp[(size_t)(base + n5 + i) * NLAYER + layer] = ps[i] + pb2v;
            }
        }
        __syncthreads();
    }
}

extern "C" void kernel_launch(void* const* d_in, const int* in_sizes, int n_in,
                              void* d_out, int out_size, void* d_ws, size_t ws_size,
                              hipStream_t stream)
{
    const float* x_vals   = (const float*)d_in[0];
    const float* x_cons   = (const float*)d_in[1];
    const float* pe_vals  = (const float*)d_in[2];
    const float* pe_cons  = (const float*)d_in[3];
    const int*   ei_v2c   = (const int*)d_in[4];   // [2,E]
    const int*   ei_c2v   = (const int*)d_in[5];   // [2,E]
    const float* ew_v2c   = (const float*)d_in[6]; // [E,1]
    const float* ew_c2v   = (const float*)d_in[7];
    const float* enc_vals_w = (const float*)d_in[8];
    const float* enc_vals_b = (const float*)d_in[9];
    const float* pe_vals_w1 = (const float*)d_in[10];
    const float* pe_vals_b1 = (const float*)d_in[11];
    const float* pe_vals_w2 = (const float*)d_in[12];
    const float* pe_vals_b2 = (const float*)d_in[13];
    const float* enc_cons_w = (const float*)d_in[14];
    const float* enc_cons_b = (const float*)d_in[15];
    const float* pe_cons_w1 = (const float*)d_in[16];
    const float* pe_cons_b1 = (const float*)d_in[17];
    const float* pe_cons_w2 = (const float*)d_in[18];
    const float* pe_cons_b2 = (const float*)d_in[19];
    const float* v2c_edge_w = (const float*)d_in[20]; // [NL,1,64]
    const float* v2c_edge_b = (const float*)d_in[21]; // [NL,64]
    const float* v2c_w1     = (const float*)d_in[22]; // [NL,64,128]
    const float* v2c_b1     = (const float*)d_in[23]; // [NL,128]
    const float* v2c_w2     = (const float*)d_in[24]; // [NL,128,64]
    const float* v2c_b2     = (const float*)d_in[25]; // [NL,64]
    const float* c2v_edge_w = (const float*)d_in[26];
    const float* c2v_edge_b = (const float*)d_in[27];
    const float* c2v_w1     = (const float*)d_in[28];
    const float* c2v_b1     = (const float*)d_in[29];
    const float* c2v_w2     = (const float*)d_in[30];
    const float* c2v_b2     = (const float*)d_in[31];
    const float* pred_vals_w1 = (const float*)d_in[32];
    const float* pred_vals_b1 = (const float*)d_in[33];
    const float* pred_vals_w2 = (const float*)d_in[34];
    const float* pred_vals_b2 = (const float*)d_in[35];
    const float* pred_cons_w1 = (const float*)d_in[36];
    const float* pred_cons_b1 = (const float*)d_in[37];
    const float* pred_cons_w2 = (const float*)d_in[38];
    const float* pred_cons_b2 = (const float*)d_in[39];

    float* out = (float*)d_out;
    float* out_c = out + (size_t)NVN * NLAYER;

    const size_t NF = (size_t)NVN * 64;

    // Workspace layout
    float* ws     = (float*)d_ws;
    float* feat_v = ws;                 // NF
    float* feat_c = feat_v + NF;        // NF
    float* oa     = feat_c + NF;        // NF
    int2* v2c_pair  = (int2*)(oa + NF);        // NE
    int2* c2v_pair  = v2c_pair + NE;           // NE
    int2* v2c_stage = c2v_pair + NE;           // NE
    int2* c2v_stage = v2c_stage + NE;          // NE
    int* ip = (int*)(c2v_stage + NE);
    int* v2c_binsz   = ip; ip += NB;    // binsz A,B adjacent -> one memset
    int* c2v_binsz   = ip; ip += NB;
    int* v2c_binbase = ip; ip += NB + 1;
    int* c2v_binbase = ip; ip += NB + 1;
    int* v2c_bincur  = ip; ip += NB;
    int* c2v_bincur  = ip; ip += NB;
    int* v2c_rowptr  = ip; ip += NCN + 1;
    int* c2v_rowptr  = ip; ip += NVN + 1;

    const int p1b = (NE + P1E - 1) / P1E;   // 245

    // CSR build (edge structure is layer-invariant)
    hipMemsetAsync(v2c_binsz, 0, (size_t)(2 * NB) * sizeof(int), stream);
    binhist_kernel<<<p1b, 256, 0, stream>>>(ei_v2c + NE, ei_c2v + NE,
                                            v2c_binsz, c2v_binsz);
    binscan_kernel<<<2, 256, 0, stream>>>(v2c_binsz, v2c_binbase, v2c_bincur,
                                          c2v_binsz, c2v_binbase, c2v_bincur);
    scatter_p1_kernel<<<p1b, 256, 0, stream>>>(
        ei_v2c, ew_v2c, v2c_bincur, v2c_stage,
        ei_c2v, ew_c2v, c2v_bincur, c2v_stage);
    scatter_p2_kernel<<<2 * NB, 1024, 0, stream>>>(
        v2c_binbase, v2c_stage, v2c_rowptr, v2c_pair,
        c2v_binbase, c2v_stage, c2v_rowptr, c2v_pair);

    // Encoders
    encode2_kernel<<<(NVN + 3) / 4 + (NCN + 3) / 4, 256, 0, stream>>>(
        x_vals, pe_vals, enc_vals_w, enc_vals_b,
        pe_vals_w1, pe_vals_b1, pe_vals_w2, pe_vals_b2,
        x_cons, pe_cons, enc_cons_w, enc_cons_b,
        pe_cons_w1, pe_cons_b1, pe_cons_w2, pe_cons_b2,
        feat_v, feat_c);

    for (int i = 0; i < NLAYER; ++i) {
        // v2c: src = vals, dst = cons
        edge_agg_kernel<<<(NCN + 3) / 4, 256, 0, stream>>>(
            feat_v, feat_c, v2c_rowptr, v2c_pair,
            v2c_edge_w + (size_t)i * HID, v2c_edge_b + (size_t)i * HID,
            oa, NCN);
        mlp_kernel<<<250, 256, 0, stream>>>(
            oa, feat_c,
            v2c_w1 + (size_t)i * 8192, v2c_b1 + (size_t)i * 128,
            v2c_w2 + (size_t)i * 8192, v2c_b2 + (size_t)i * 64,
            pred_cons_w1, pred_cons_b1, pred_cons_w2, pred_cons_b2,
            out_c, NCN, i);
        // c2v: src = cons (updated), dst = vals
        edge_agg_kernel<<<(NVN + 3) / 4, 256, 0, stream>>>(
            feat_c, feat_v, c2v_rowptr, c2v_pair,
            c2v_edge_w + (size_t)i * HID, c2v_edge_b + (size_t)i * HID,
            oa, NVN);
        mlp_kernel<<<250, 256, 0, stream>>>(
            oa, feat_v,
            c2v_w1 + (size_t)i * 8192, c2v_b1 + (size_t)i * 128,
            c2v_w2 + (size_t)i * 8192, c2v_b2 + (size_t)i * 64,
            pred_vals_w1, pred_vals_b1, pred_vals_w2, pred_vals_b2,
            out, NVN, i);
    }
}